// Round 4
// baseline (500.075 us; speedup 1.0000x reference)
//
#include <hip/hip_runtime.h>
#include <hip/hip_cooperative_groups.h>

// H2G2: 2-layer RGCN (R=4, per-relation mean) + mean-pool + linear.
// R10: register-resident fused layer (231us total, layer 47us). R11 FAILED:
//   launch_bounds(256,4) VGPR cap -> scratch spill (layer 221us). Never cap.
// R12 (229.6us): channel-split wave pair, merged one-hot loop, 8KB LDS
//   exchange: layer pinned at 47.0us == R10. FETCH 52MB = 8 XCD x 6.4MB full
//   per-XCD L2 replication at ~1 line/cy/XCD -> layer is L2-FILL-BOUND.
// R13 FAILED (282.6us): count+scan+place direct CSR; place = 55us, WRITE 54MB
//   = ExLINE random 4B eidx writes -> full-line RMW. Bucket sort was right.
//   KEY ARITHMETIC: R12 non-layer 135.6us ~= R13's 133.6 (different kernels!)
//   minus ~65us of per-kernel estimates -> ~10us inter-dispatch gap x 7
//   launches dominates. Serial dependency chain -> gaps not overlappable.
// R14: ONE cooperative mega-kernel, grid.sync() between phases (guide: harness
//   supports hipLaunchCooperativeKernel). Phases: init/weights/conv/hist ->
//   bin (direct scatter, LDS staging dropped; within-bucket order irrelevant)
//   -> csr (direct eidx scatter, rpflat int4, inv deleted) -> layer1 ->
//   layer2 -> pool. Max LDS 8KB (xpack), layer VGPR ~60 -> 7 blocks/CU -> 1563
//   blocks resident. phase>=0 = single-phase normal launch (fallback path).

#define RR 4
#define HH 64
#define KK 320         // (RR+1)*HH
#define LWN (HH * KK)  // weights per layer = 20480
#define EPB 4096       // edges per histogram/bin chunk

namespace cg = cooperative_groups;

using frag_ab = __attribute__((ext_vector_type(8))) short;
using frag_cd = __attribute__((ext_vector_type(4))) float;

__device__ inline short f2bf(float f) {
    unsigned u = __builtin_bit_cast(unsigned, f);
    unsigned r = u + 0x7fffu + ((u >> 16) & 1u);  // RNE
    return (short)(r >> 16);
}
__device__ inline float bf2f(short s) {
    unsigned u = ((unsigned)(unsigned short)s) << 16;
    return __builtin_bit_cast(float, u);
}

union SMem {
    struct { int lc[256]; } ph0;
    struct { int ss[256]; int lc[256]; int lbase[256]; int lc2[256]; } bin;
    struct { int cnt4l[1024]; int ss[256]; } csr;
    short xpack[2][64][32];   // 8KB — the max member
    float red[4][64];
};

// ---- fused layer body (R12 structure, grid-stride, no early return) ----
__device__ __forceinline__ void layer_body(
    short (*xpack)[64][32],
    const int* __restrict__ rpflat, const int* __restrict__ eidx,
    const short* __restrict__ Xb, const short* __restrict__ Wt,
    const float* __restrict__ bias, short* __restrict__ out,
    int n, int nchunks) {
    const int t = threadIdx.x;
    const int wv = t >> 6;
    const int pair = wv >> 1;   // which 16-node group
    const int ws = wv & 1;      // channel half: 0 = quad*8, 1 = 32+quad*8
    const int l = t & 63;
    const int m = l & 15;
    const int quad = l >> 4;

    for (int chunk = blockIdx.x; chunk < nchunks; chunk += gridDim.x) {
        const int node = chunk * 32 + pair * 16 + m;
        const bool valid = node < n;

        float acc[4][8];
#pragma unroll
        for (int r = 0; r < 4; ++r)
#pragma unroll
            for (int j = 0; j < 8; ++j) acc[r][j] = 0.f;

        int k0 = 0, k1 = 0;
        float4 iv = make_float4(0.f, 0.f, 0.f, 0.f);
        if (valid) {
            int4 r4 = *(const int4*)&rpflat[node * 4];
            int kend = rpflat[node * 4 + 4];
            k0 = r4.x;
            k1 = kend;
            iv.x = 1.0f / fmaxf((float)(r4.y - r4.x), 1.0f);
            iv.y = 1.0f / fmaxf((float)(r4.z - r4.y), 1.0f);
            iv.z = 1.0f / fmaxf((float)(r4.w - r4.z), 1.0f);
            iv.w = 1.0f / fmaxf((float)(kend - r4.w), 1.0f);
        }
        const short* xbq = Xb + ws * 32 + quad * 8;

#define ACC(P, F)                                                             \
    {                                                                         \
        int r_ = (P) & 3;                                                     \
        float s0_ = (r_ == 0) ? 1.f : 0.f;                                    \
        float s1_ = (r_ == 1) ? 1.f : 0.f;                                    \
        float s2_ = (r_ == 2) ? 1.f : 0.f;                                    \
        float s3_ = (r_ == 3) ? 1.f : 0.f;                                    \
        _Pragma("unroll") for (int j = 0; j < 8; ++j) {                       \
            float v_ = bf2f((F)[j]);                                          \
            acc[0][j] += v_ * s0_;                                            \
            acc[1][j] += v_ * s1_;                                            \
            acc[2][j] += v_ * s2_;                                            \
            acc[3][j] += v_ * s3_;                                            \
        }                                                                     \
    }

        int k = k0;
        for (; k + 3 < k1; k += 4) {  // 4 edges in flight
            int p0 = eidx[k];
            int p1 = eidx[k + 1];
            int p2 = eidx[k + 2];
            int p3 = eidx[k + 3];
            const short* a0p = xbq + (size_t)(p0 >> 2) * 64;
            const short* a1p = xbq + (size_t)(p1 >> 2) * 64;
            const short* a2p = xbq + (size_t)(p2 >> 2) * 64;
            const short* a3p = xbq + (size_t)(p3 >> 2) * 64;
            frag_ab f0 = *(const frag_ab*)a0p;
            frag_ab f1 = *(const frag_ab*)a1p;
            frag_ab f2 = *(const frag_ab*)a2p;
            frag_ab f3 = *(const frag_ab*)a3p;
            ACC(p0, f0)
            ACC(p1, f1)
            ACC(p2, f2)
            ACC(p3, f3)
        }
        for (; k < k1; ++k) {
            int p0 = eidx[k];
            const short* a0p = xbq + (size_t)(p0 >> 2) * 64;
            frag_ab f0 = *(const frag_ab*)a0p;
            ACC(p0, f0)
        }
#undef ACC

        frag_ab y[4];
        {
            float s0 = iv.x, s1 = iv.y, s2 = iv.z, s3 = iv.w;
#pragma unroll
            for (int j = 0; j < 8; ++j) {
                y[0][j] = f2bf(acc[0][j] * s0);
                y[1][j] = f2bf(acc[1][j] * s1);
                y[2][j] = f2bf(acc[2][j] * s2);
                y[3][j] = f2bf(acc[3][j] * s3);
            }
        }

        if (ws == 1) {
#pragma unroll
            for (int r = 0; r < 4; ++r)
                *(frag_ab*)&xpack[pair][l][r * 8] = y[r];
        }
        __syncthreads();
        if (ws == 0) {
            frag_ab a[10];
            a[0] = frag_ab{};
            a[1] = frag_ab{};
            if (valid) {
                const short* xr = Xb + (size_t)node * 64 + quad * 8;
                a[0] = *(const frag_ab*)xr;
                a[1] = *(const frag_ab*)(xr + 32);
            }
#pragma unroll
            for (int r = 0; r < 4; ++r) {
                a[2 + 2 * r] = y[r];
                a[3 + 2 * r] = *(const frag_ab*)&xpack[pair][l][r * 8];
            }

            const int nrow_base = chunk * 32 + pair * 16 + quad * 4;
#pragma unroll
            for (int ct = 0; ct < 4; ++ct) {
                const short* bp = Wt + (size_t)(ct * 16 + m) * KK + quad * 8;
                frag_cd c = {0.f, 0.f, 0.f, 0.f};
#pragma unroll
                for (int f = 0; f < 10; ++f) {
                    frag_ab bf = *(const frag_ab*)(bp + f * 32);
                    c = __builtin_amdgcn_mfma_f32_16x16x32_bf16(a[f], bf, c, 0, 0, 0);
                }
                int col = ct * 16 + m;
                float bv = bias[col];
#pragma unroll
                for (int r = 0; r < 4; ++r) {
                    int nr = nrow_base + r;
                    if (nr < n) out[(size_t)nr * 64 + col] = f2bf(fmaxf(c[r] + bv, 0.f));
                }
            }
        }
        __syncthreads();  // protect xpack reuse across chunks
    }
}

// ---- mega kernel: phase==-1 runs all phases with grid.sync() (cooperative);
//      phase>=0 runs a single phase (normal-launch fallback) ----
__global__ __launch_bounds__(256) void mega_kernel(
    const int* __restrict__ src, const int* __restrict__ dst,
    const int* __restrict__ et, int E,
    const float* __restrict__ basis1, const float* __restrict__ comp1,
    const float* __restrict__ root1, const float* __restrict__ basis2,
    const float* __restrict__ comp2, const float* __restrict__ root2,
    short* __restrict__ W1t, short* __restrict__ W2t,
    const float* __restrict__ bias1, const float* __restrict__ bias2,
    const int* __restrict__ batch, int* __restrict__ gstart, int N, int G,
    const float* __restrict__ x, short* __restrict__ Xb,
    int* __restrict__ hpart, int* __restrict__ cur0,
    int* __restrict__ bstart, int* __restrict__ blen,
    int* __restrict__ tmp, int* __restrict__ rpflat, int* __restrict__ eidx,
    short* __restrict__ H1, short* __restrict__ H2,
    const float* __restrict__ clas_w, const float* __restrict__ clas_b,
    float* __restrict__ gout,
    int ebl, int nbuck, int nchunks, int phase) {
    __shared__ SMem sm;
    const int t = threadIdx.x;
    const int bid = blockIdx.x;
    const int T = gridDim.x * 256;
    const int tid = bid * 256 + t;

    // ---------------- phase 0: init / weights / gstart / conv / histogram ----
    if (phase == -1 || phase == 0) {
        if (bid < ebl) {  // per-chunk dst>>8 histogram -> hpart
            sm.ph0.lc[t] = 0;
            __syncthreads();
            int e0 = bid * EPB, e1 = min(e0 + EPB, E);
            for (int e = e0 + t; e < e1; e += 256) atomicAdd(&sm.ph0.lc[dst[e] >> 8], 1);
            __syncthreads();
            hpart[bid * 256 + t] = sm.ph0.lc[t];
        }
        if (bid == gridDim.x - 1) cur0[t] = 0;
        if (tid == 0) rpflat[4 * N] = E;  // sentinel
        for (int w = tid; w < 2 * LWN; w += T) {  // weights Wt[c*320+k]
            int layer = w / LWN;
            int rem = w - layer * LWN;
            int c = rem / KK;
            int k = rem - c * KK;
            const float* basis = layer ? basis2 : basis1;
            const float* comp  = layer ? comp2  : comp1;
            const float* root  = layer ? root2  : root1;
            short* Wt          = layer ? W2t    : W1t;
            float v;
            if (k < HH) {
                v = root[k * HH + c];
            } else {
                int r = (k >> 6) - 1, kk = k & 63;
                v = 0.f;
#pragma unroll
                for (int b = 0; b < RR; ++b) v += comp[r * RR + b] * basis[(b * HH + kk) * HH + c];
            }
            Wt[c * KK + k] = f2bf(v);
        }
        for (int i = tid; i < N; i += T) {  // gstart
            int b1 = batch[i];
            int b0 = (i == 0) ? -1 : batch[i - 1];
            for (int g = b0 + 1; g <= b1; ++g) gstart[g] = i;
            if (i == N - 1)
                for (int g = b1 + 1; g <= G; ++g) gstart[g] = N;
        }
        for (int i4 = tid; i4 < N * 16; i4 += T) {  // x fp32 -> bf16
            int base = i4 * 4;
            float4 f = *(const float4*)&x[base];
            short4 s;
            s.x = f2bf(f.x); s.y = f2bf(f.y); s.z = f2bf(f.z); s.w = f2bf(f.w);
            *(short4*)&Xb[base] = s;
        }
    }
    if (phase == -1) cg::this_grid().sync();

    // ---------------- phase 1: bin (bucket scatter into tmp) ----------------
    if ((phase == -1 || phase == 1) && bid < ebl) {
        int bv = 0;
        for (int b = 0; b < ebl; ++b) bv += hpart[b * 256 + t];  // column sum
        sm.bin.ss[t] = bv;
        __syncthreads();
#pragma unroll
        for (int off = 1; off < 256; off <<= 1) {
            int u = (t >= off) ? sm.bin.ss[t - off] : 0;
            __syncthreads();
            sm.bin.ss[t] += u;
            __syncthreads();
        }
        int boff = sm.bin.ss[t] - bv;
        if (bid == 0) { bstart[t] = boff; blen[t] = bv; }
        sm.bin.lc[t] = 0;
        __syncthreads();
        int e0 = bid * EPB, e1 = min(e0 + EPB, E);
        for (int e = e0 + t; e < e1; e += 256) atomicAdd(&sm.bin.lc[dst[e] >> 8], 1);
        __syncthreads();
        int v = sm.bin.lc[t];
        sm.bin.lbase[t] = v ? boff + atomicAdd(&cur0[t], v) : 0;
        sm.bin.lc2[t] = 0;
        __syncthreads();
        for (int e = e0 + t; e < e1; e += 256) {
            int d = dst[e];
            int b = d >> 8;
            int p = (src[e] << 10) | (et[e] << 8) | (d & 255);
            int pos = sm.bin.lbase[b] + atomicAdd(&sm.bin.lc2[b], 1);
            tmp[pos] = p;
        }
    }
    if (phase == -1) cg::this_grid().sync();

    // ---------------- phase 2: csr (per-bucket (dl,rel) sort -> rpflat/eidx) -
    if ((phase == -1 || phase == 2) && bid < nbuck) {
        int s0 = bstart[bid], len = blen[bid], s1 = s0 + len;
        for (int i = t; i < 1024; i += 256) sm.csr.cnt4l[i] = 0;
        __syncthreads();
        for (int i = s0 + t; i < s1; i += 256) {
            int e = tmp[i];
            atomicAdd(&sm.csr.cnt4l[((e & 255) << 2) | ((e >> 8) & 3)], 1);
        }
        __syncthreads();
        int c0 = sm.csr.cnt4l[t * 4], c1 = sm.csr.cnt4l[t * 4 + 1];
        int c2 = sm.csr.cnt4l[t * 4 + 2], c3 = sm.csr.cnt4l[t * 4 + 3];
        int deg = c0 + c1 + c2 + c3;
        sm.csr.ss[t] = deg;
        __syncthreads();
#pragma unroll
        for (int off = 1; off < 256; off <<= 1) {
            int u = (t >= off) ? sm.csr.ss[t - off] : 0;
            __syncthreads();
            sm.csr.ss[t] += u;
            __syncthreads();
        }
        int a0 = s0 + sm.csr.ss[t] - deg;
        int d = (bid << 8) + t;
        if (d < N)
            *(int4*)&rpflat[d * 4] = make_int4(a0, a0 + c0, a0 + c0 + c1, a0 + c0 + c1 + c2);
        sm.csr.cnt4l[t * 4]     = a0;
        sm.csr.cnt4l[t * 4 + 1] = a0 + c0;
        sm.csr.cnt4l[t * 4 + 2] = a0 + c0 + c1;
        sm.csr.cnt4l[t * 4 + 3] = a0 + c0 + c1 + c2;
        __syncthreads();
        for (int i = s0 + t; i < s1; i += 256) {
            int e = tmp[i];
            int key = ((e & 255) << 2) | ((e >> 8) & 3);
            int pos = atomicAdd(&sm.csr.cnt4l[key], 1);
            eidx[pos] = ((e >> 10) << 2) | ((e >> 8) & 3);
        }
    }
    if (phase == -1) cg::this_grid().sync();

    // ---------------- phase 3/4: layers ----------------
    if (phase == -1 || phase == 3)
        layer_body(sm.xpack, rpflat, eidx, Xb, W1t, bias1, H1, N, nchunks);
    if (phase == -1) cg::this_grid().sync();
    if (phase == -1 || phase == 4)
        layer_body(sm.xpack, rpflat, eidx, H1, W2t, bias2, H2, N, nchunks);
    if (phase == -1) cg::this_grid().sync();

    // ---------------- phase 5: pool + classifier ----------------
    if (phase == -1 || phase == 5) {
        const int h = t & 63;
        const int wv = t >> 6;
        for (int g = bid; g < G; g += gridDim.x) {
            const int s = gstart[g], e = gstart[g + 1];
            float acc = 0.f;
            for (int i = s + wv; i < e; i += 4) acc += bf2f(H2[(size_t)i * 64 + h]);
            sm.red[wv][h] = acc;
            __syncthreads();
            if (wv == 0) {
                float sum = sm.red[0][h] + sm.red[1][h] + sm.red[2][h] + sm.red[3][h];
                sm.red[0][h] = sum / fmaxf((float)(e - s), 1.0f);
            }
            __syncthreads();
            if (t < 4) {
                float sres = 0.f;
#pragma unroll 8
                for (int hh = 0; hh < 64; ++hh) sres += sm.red[0][hh] * clas_w[hh * 4 + t];
                gout[g * 4 + t] = sres + clas_b[t];
            }
            __syncthreads();
        }
    }
}

extern "C" void kernel_launch(void* const* d_in, const int* in_sizes, int n_in,
                              void* d_out, int out_size, void* d_ws, size_t ws_size,
                              hipStream_t stream) {
    const float* x        = (const float*)d_in[0];
    const int* edge_index = (const int*)d_in[1];
    const int* edge_type  = (const int*)d_in[2];
    const int* batch      = (const int*)d_in[3];
    const float* basis1 = (const float*)d_in[4];
    const float* comp1  = (const float*)d_in[5];
    const float* root1  = (const float*)d_in[6];
    const float* bias1  = (const float*)d_in[7];
    const float* basis2 = (const float*)d_in[8];
    const float* comp2  = (const float*)d_in[9];
    const float* root2  = (const float*)d_in[10];
    const float* bias2  = (const float*)d_in[11];
    const float* clas_w = (const float*)d_in[12];
    const float* clas_b = (const float*)d_in[13];

    const int N = in_sizes[0] / 64;
    const int E = in_sizes[2];
    const int G = out_size / 4;
    const int* src = edge_index;
    const int* dst = edge_index + E;
    const int nbuck = (N + 255) >> 8;
    const int ebl = (E + EPB - 1) / EPB;
    const int nchunks = (N + 31) / 32;

    char* base = (char*)d_ws;
    size_t off = 0;
    auto carve = [&](size_t bytes) { void* p = base + off; off = (off + bytes + 15) & ~(size_t)15; return p; };
    int*   hpart   = (int*)carve(sizeof(int) * (size_t)ebl * 256);
    int*   cur0    = (int*)carve(sizeof(int) * 256);
    int*   bstart  = (int*)carve(sizeof(int) * 256);
    int*   blen    = (int*)carve(sizeof(int) * 256);
    int*   rpflat  = (int*)carve(sizeof(int) * ((size_t)N * 4 + 4));
    int*   gstart  = (int*)carve(sizeof(int) * ((size_t)G + 1));
    int*   eidx    = (int*)carve(sizeof(int) * (size_t)E);
    int*   tmp     = (int*)carve(sizeof(int) * (size_t)E);
    short* W1t     = (short*)carve(sizeof(short) * LWN);
    short* W2t     = (short*)carve(sizeof(short) * LWN);
    short* Xb1     = (short*)carve(sizeof(short) * (size_t)N * 64);
    short* H1      = (short*)carve(sizeof(short) * (size_t)N * 64);
    short* H2      = (short*)carve(sizeof(short) * (size_t)N * 64);
    float* gout    = (float*)d_out;

    int E_ = E, N_ = N, G_ = G, ebl_ = ebl, nbuck_ = nbuck, nchunks_ = nchunks;
    int phase = -1;

    void* args[] = {
        (void*)&src, (void*)&dst, (void*)&edge_type, (void*)&E_,
        (void*)&basis1, (void*)&comp1, (void*)&root1,
        (void*)&basis2, (void*)&comp2, (void*)&root2,
        (void*)&W1t, (void*)&W2t, (void*)&bias1, (void*)&bias2,
        (void*)&batch, (void*)&gstart, (void*)&N_, (void*)&G_,
        (void*)&x, (void*)&Xb1,
        (void*)&hpart, (void*)&cur0, (void*)&bstart, (void*)&blen,
        (void*)&tmp, (void*)&rpflat, (void*)&eidx,
        (void*)&H1, (void*)&H2, (void*)&clas_w, (void*)&clas_b, (void*)&gout,
        (void*)&ebl_, (void*)&nbuck_, (void*)&nchunks_, (void*)&phase};

    int maxB = 0;
    hipError_t qerr = hipOccupancyMaxActiveBlocksPerMultiprocessor(
        &maxB, (const void*)mega_kernel, 256, 0);
    bool coop_ok = false;
    if (qerr == hipSuccess && maxB >= 1) {
        int grid = maxB * 256;  // 256 CUs on MI355X
        if (grid > nchunks) grid = nchunks;
        hipError_t lerr = hipLaunchCooperativeKernel(
            (const void*)mega_kernel, dim3(grid), dim3(256), args, 0, stream);
        coop_ok = (lerr == hipSuccess);
    }
    if (!coop_ok) {
        // fallback: phase-by-phase normal launches (identical semantics)
        const int grids[6] = {nchunks, ebl, nbuck, nchunks, nchunks, G};
        for (int p = 0; p < 6; ++p) {
            mega_kernel<<<grids[p], 256, 0, stream>>>(
                src, dst, edge_type, E_,
                basis1, comp1, root1, basis2, comp2, root2,
                W1t, W2t, bias1, bias2,
                batch, gstart, N_, G_, x, Xb1,
                hpart, cur0, bstart, blen, tmp, rpflat, eidx,
                H1, H2, clas_w, clas_b, gout,
                ebl_, nbuck_, nchunks_, p);
        }
    }
}

// Round 5
// 314.099 us; speedup vs baseline: 1.5921x; 1.5921x over previous
//
#include <hip/hip_runtime.h>

// H2G2: 2-layer RGCN (R=4, per-relation mean) + mean-pool + linear.
// R10: register-resident fused layer (231us total, layer 47us). R11 FAILED:
//   launch_bounds(256,4) VGPR cap -> scratch spill (layer 221us). Never cap.
// R12 (229.6us): channel-split wave pair, merged one-hot loop, 8KB LDS
//   exchange: layer pinned at 47.0us == R10. FETCH 52MB = 8 XCD x 6.4MB full
//   per-XCD L2 replication at ~1 line/cy/XCD -> layer is L2-FILL-BOUND.
// R13 FAILED (282.6us): place_kernel random 4B eidx writes = full-line RMW
//   (WRITE 54MB, 55us). Bucket-staged writes were right. Gap math: ~10-12us
//   per dispatch x 7-8 dispatches dominates non-layer time.
// R14 FAILED (500us+): cooperative mega-kernel; grid.sync ~80-90us each when
//   grid mostly idle (1340 spinning blocks = device-scope atomic storm on one
//   line, starves the 196 working blocks). NEVER grid-sync to save 10us gaps.
// R15: cut dispatches 7 -> 5 without any grid sync:
//   (a) fixed-CAP buckets (CAP=6144/bucket, mean 4096): bin reserves space
//       via atomicAdd(&cur[b], cnt) -> prep histogram + memset + global scan
//       deleted; csr scans cur[256] in-block for compact eidx starts.
//   (b) layer2 fuses pool+classifier: no H2; fp32 relu outputs atomicAdd into
//       gsum[G][64]; done-counter elects last block to classify (device-scope
//       loads). Deletes pool dispatch + 12.8MB of H2 traffic.
//   EPB 4096 -> 2048 (391 bin blocks, 2x parallelism).

#define RR 4
#define HH 64
#define KK 320         // (RR+1)*HH
#define LWN (HH * KK)  // weights per layer = 20480
#define EPB 2048       // edges per bin chunk
#define CAP 6144       // per-bucket fixed capacity (mean 4096, +32 sigma)

using frag_ab = __attribute__((ext_vector_type(8))) short;
using frag_cd = __attribute__((ext_vector_type(4))) float;

__device__ inline short f2bf(float f) {
    unsigned u = __builtin_bit_cast(unsigned, f);
    unsigned r = u + 0x7fffu + ((u >> 16) & 1u);  // RNE
    return (short)(r >> 16);
}
__device__ inline float bf2f(short s) {
    unsigned u = ((unsigned)(unsigned short)s) << 16;
    return __builtin_bit_cast(float, u);
}

// ---- prep: zero | weights | gstart+sentinel | x conv ----
__global__ __launch_bounds__(256) void prep_kernel(
    const float* __restrict__ basis1, const float* __restrict__ comp1, const float* __restrict__ root1,
    const float* __restrict__ basis2, const float* __restrict__ comp2, const float* __restrict__ root2,
    short* __restrict__ W1t, short* __restrict__ W2t,
    const int* __restrict__ batch, int* __restrict__ gstart, int N, int G,
    const float* __restrict__ x, short* __restrict__ Xb,
    int* __restrict__ cur, float* __restrict__ gsum, int* __restrict__ done,
    int* __restrict__ rpflat, int E,
    int zb, int wbl, int nb) {
    const int bid = blockIdx.x;
    const int t = threadIdx.x;
    if (bid < zb) {  // ---- zero gsum / cur / done ----
        int i = bid * 256 + t;
        if (i < G * HH) gsum[i] = 0.f;
        if (bid == 0) {
            cur[t] = 0;
            if (t == 0) *done = 0;
        }
    } else if (bid < zb + wbl) {  // ---- weights: Wt[c*320+k] = Wstack[k][c] ----
        int w = (bid - zb) * 256 + t;
        int layer = w / LWN;
        int rem = w - layer * LWN;
        int c = rem / KK;
        int k = rem - c * KK;
        const float* basis = layer ? basis2 : basis1;
        const float* comp  = layer ? comp2  : comp1;
        const float* root  = layer ? root2  : root1;
        short* Wt          = layer ? W2t    : W1t;
        float v;
        if (k < HH) {
            v = root[k * HH + c];
        } else {
            int r = (k >> 6) - 1, kk = k & 63;
            v = 0.f;
#pragma unroll
            for (int b = 0; b < RR; ++b) v += comp[r * RR + b] * basis[(b * HH + kk) * HH + c];
        }
        Wt[c * KK + k] = f2bf(v);
    } else if (bid < zb + wbl + nb) {  // ---- gstart + rpflat sentinel ----
        int i = (bid - zb - wbl) * 256 + t;
        if (i == 0) rpflat[4 * N] = E;
        if (i < N) {
            int b1 = batch[i];
            int b0 = (i == 0) ? -1 : batch[i - 1];
            for (int g = b0 + 1; g <= b1; ++g) gstart[g] = i;
            if (i == N - 1)
                for (int g = b1 + 1; g <= G; ++g) gstart[g] = N;
        }
    } else {  // ---- convert x fp32 -> bf16 ----
        int i4 = (bid - zb - wbl - nb) * 256 + t;
        int base = i4 * 4;
        if (base < N * 64) {
            float4 f = *(const float4*)&x[base];
            short4 s;
            s.x = f2bf(f.x); s.y = f2bf(f.y); s.z = f2bf(f.z); s.w = f2bf(f.w);
            *(short4*)&Xb[base] = s;
        }
    }
}

// ---- bin: LDS-staged bucket scatter into fixed-CAP tmp regions ----
__global__ __launch_bounds__(256) void bin_kernel(const int* __restrict__ src,
                                                  const int* __restrict__ dst,
                                                  const int* __restrict__ et,
                                                  int* __restrict__ cur,
                                                  int* __restrict__ tmp, int E) {
    __shared__ int ss[256];
    __shared__ int lscan[257];
    __shared__ int lbase[256];
    __shared__ int lc2[256];
    __shared__ int sbuf[EPB];
    const int t = threadIdx.x;
    const int e0 = blockIdx.x * EPB;
    const int e1 = min(e0 + EPB, E);

    ss[t] = 0;  // reuse ss as histogram first
    __syncthreads();
    for (int e = e0 + t; e < e1; e += 256) atomicAdd(&ss[dst[e] >> 8], 1);
    __syncthreads();
    int v = ss[t];
    __syncthreads();
    ss[t] = v;
    __syncthreads();
#pragma unroll
    for (int off = 1; off < 256; off <<= 1) {
        int u = (t >= off) ? ss[t - off] : 0;
        __syncthreads();
        ss[t] += u;
        __syncthreads();
    }
    lscan[t] = ss[t] - v;
    if (t == 255) lscan[256] = ss[255];
    // reserve global space in bucket t
    lbase[t] = v ? t * CAP + atomicAdd(&cur[t], v) : 0;
    lc2[t] = 0;
    __syncthreads();
    for (int e = e0 + t; e < e1; e += 256) {
        int d = dst[e];
        int b = d >> 8;
        int p = (src[e] << 10) | (et[e] << 8) | (d & 255);
        int pos = lscan[b] + atomicAdd(&lc2[b], 1);
        sbuf[pos] = p;
    }
    __syncthreads();
    int tot = lscan[256];
    for (int i = t; i < tot; i += 256) {
        int lo = 0, hi = 255;
        while (lo < hi) { int mid = (lo + hi + 1) >> 1; if (lscan[mid] <= i) lo = mid; else hi = mid - 1; }
        int idx = lbase[lo] + (i - lscan[lo]);
        if (idx - lo * CAP < CAP) tmp[idx] = sbuf[i];  // overflow shield
    }
}

// ---- csr: per-bucket (dl,rel) counting sort -> rpflat int4 + compact eidx ----
__global__ __launch_bounds__(256) void csr_kernel(const int* __restrict__ cur,
                                                  const int* __restrict__ tmp,
                                                  int* __restrict__ rpflat,
                                                  int* __restrict__ eidx, int N) {
    __shared__ int cnt4l[1024];
    __shared__ int ss[256];
    __shared__ int s0s, lens;
    const int b = blockIdx.x;
    const int t = threadIdx.x;
    // compact global start: scan bucket lengths
    int lv = min(cur[t], CAP);
    ss[t] = lv;
    __syncthreads();
#pragma unroll
    for (int off = 1; off < 256; off <<= 1) {
        int u = (t >= off) ? ss[t - off] : 0;
        __syncthreads();
        ss[t] += u;
        __syncthreads();
    }
    if (t == b) { s0s = ss[t] - lv; lens = lv; }
    __syncthreads();
    const int s0 = s0s, len = lens;
    const int tb = b * CAP;

    for (int i = t; i < 1024; i += 256) cnt4l[i] = 0;
    __syncthreads();
    for (int i = t; i < len; i += 256) {
        int e = tmp[tb + i];
        atomicAdd(&cnt4l[((e & 255) << 2) | ((e >> 8) & 3)], 1);
    }
    __syncthreads();
    int c0 = cnt4l[t * 4], c1 = cnt4l[t * 4 + 1], c2 = cnt4l[t * 4 + 2], c3 = cnt4l[t * 4 + 3];
    int deg = c0 + c1 + c2 + c3;
    ss[t] = deg;
    __syncthreads();
#pragma unroll
    for (int off = 1; off < 256; off <<= 1) {
        int u = (t >= off) ? ss[t - off] : 0;
        __syncthreads();
        ss[t] += u;
        __syncthreads();
    }
    int a0 = s0 + ss[t] - deg;
    int d = (b << 8) + t;
    if (d < N)
        *(int4*)&rpflat[d * 4] = make_int4(a0, a0 + c0, a0 + c0 + c1, a0 + c0 + c1 + c2);
    cnt4l[t * 4]     = a0;
    cnt4l[t * 4 + 1] = a0 + c0;
    cnt4l[t * 4 + 2] = a0 + c0 + c1;
    cnt4l[t * 4 + 3] = a0 + c0 + c1 + c2;
    __syncthreads();
    for (int i = t; i < len; i += 256) {
        int e = tmp[tb + i];
        int key = ((e & 255) << 2) | ((e >> 8) & 3);
        int pos = atomicAdd(&cnt4l[key], 1);
        eidx[pos] = ((e >> 10) << 2) | ((e >> 8) & 3);
    }
}

// ---- fused layer: R12 body. do_pool: no out store; fp32 relu -> gsum
//      atomics; last block classifies. ----
__global__ __launch_bounds__(256) void layer_kernel(
    const int* __restrict__ rpflat,
    const int* __restrict__ eidx,
    const short* __restrict__ Xb,
    const short* __restrict__ Wt,
    const float* __restrict__ bias,
    short* __restrict__ out, int n, int do_pool,
    const int* __restrict__ batch, float* __restrict__ gsum,
    int* __restrict__ done, const int* __restrict__ gstart, int G,
    const float* __restrict__ clas_w, const float* __restrict__ clas_b,
    float* __restrict__ gout) {
    __shared__ short xpack[2][64][32];  // 8KB
    __shared__ int winner;
    const int t = threadIdx.x;
    const int wv = t >> 6;
    const int pair = wv >> 1;   // which 16-node group
    const int ws = wv & 1;      // channel half: 0 = quad*8, 1 = 32+quad*8
    const int l = t & 63;
    const int m = l & 15;
    const int quad = l >> 4;
    const int node = blockIdx.x * 32 + pair * 16 + m;
    const bool valid = node < n;

    float acc[4][8];
#pragma unroll
    for (int r = 0; r < 4; ++r)
#pragma unroll
        for (int j = 0; j < 8; ++j) acc[r][j] = 0.f;

    int k0 = 0, k1 = 0;
    float4 iv = make_float4(0.f, 0.f, 0.f, 0.f);
    if (valid) {
        int4 r4 = *(const int4*)&rpflat[node * 4];
        int kend = rpflat[node * 4 + 4];
        k0 = r4.x;
        k1 = kend;
        iv.x = 1.0f / fmaxf((float)(r4.y - r4.x), 1.0f);
        iv.y = 1.0f / fmaxf((float)(r4.z - r4.y), 1.0f);
        iv.z = 1.0f / fmaxf((float)(r4.w - r4.z), 1.0f);
        iv.w = 1.0f / fmaxf((float)(kend - r4.w), 1.0f);
    }
    const short* xbq = Xb + ws * 32 + quad * 8;

#define ACC(P, F)                                                             \
    {                                                                         \
        int r_ = (P) & 3;                                                     \
        float s0_ = (r_ == 0) ? 1.f : 0.f;                                    \
        float s1_ = (r_ == 1) ? 1.f : 0.f;                                    \
        float s2_ = (r_ == 2) ? 1.f : 0.f;                                    \
        float s3_ = (r_ == 3) ? 1.f : 0.f;                                    \
        _Pragma("unroll") for (int j = 0; j < 8; ++j) {                       \
            float v_ = bf2f((F)[j]);                                          \
            acc[0][j] += v_ * s0_;                                            \
            acc[1][j] += v_ * s1_;                                            \
            acc[2][j] += v_ * s2_;                                            \
            acc[3][j] += v_ * s3_;                                            \
        }                                                                     \
    }

    int k = k0;
    for (; k + 3 < k1; k += 4) {  // 4 edges in flight
        int p0 = eidx[k];
        int p1 = eidx[k + 1];
        int p2 = eidx[k + 2];
        int p3 = eidx[k + 3];
        const short* a0p = xbq + (size_t)(p0 >> 2) * 64;
        const short* a1p = xbq + (size_t)(p1 >> 2) * 64;
        const short* a2p = xbq + (size_t)(p2 >> 2) * 64;
        const short* a3p = xbq + (size_t)(p3 >> 2) * 64;
        frag_ab f0 = *(const frag_ab*)a0p;
        frag_ab f1 = *(const frag_ab*)a1p;
        frag_ab f2 = *(const frag_ab*)a2p;
        frag_ab f3 = *(const frag_ab*)a3p;
        ACC(p0, f0)
        ACC(p1, f1)
        ACC(p2, f2)
        ACC(p3, f3)
    }
    for (; k < k1; ++k) {
        int p0 = eidx[k];
        const short* a0p = xbq + (size_t)(p0 >> 2) * 64;
        frag_ab f0 = *(const frag_ab*)a0p;
        ACC(p0, f0)
    }
#undef ACC

    frag_ab y[4];
    {
        float s0 = iv.x, s1 = iv.y, s2 = iv.z, s3 = iv.w;
#pragma unroll
        for (int j = 0; j < 8; ++j) {
            y[0][j] = f2bf(acc[0][j] * s0);
            y[1][j] = f2bf(acc[1][j] * s1);
            y[2][j] = f2bf(acc[2][j] * s2);
            y[3][j] = f2bf(acc[3][j] * s3);
        }
    }

    if (ws == 1) {
#pragma unroll
        for (int r = 0; r < 4; ++r)
            *(frag_ab*)&xpack[pair][l][r * 8] = y[r];
    }
    __syncthreads();
    if (ws == 0) {
        frag_ab a[10];
        a[0] = frag_ab{};
        a[1] = frag_ab{};
        if (valid) {
            const short* xr = Xb + (size_t)node * 64 + quad * 8;
            a[0] = *(const frag_ab*)xr;
            a[1] = *(const frag_ab*)(xr + 32);
        }
#pragma unroll
        for (int r = 0; r < 4; ++r) {
            a[2 + 2 * r] = y[r];
            a[3 + 2 * r] = *(const frag_ab*)&xpack[pair][l][r * 8];
        }

        const int nrow_base = blockIdx.x * 32 + pair * 16 + quad * 4;
#pragma unroll
        for (int ct = 0; ct < 4; ++ct) {
            const short* bp = Wt + (size_t)(ct * 16 + m) * KK + quad * 8;
            frag_cd c = {0.f, 0.f, 0.f, 0.f};
#pragma unroll
            for (int f = 0; f < 10; ++f) {
                frag_ab bf = *(const frag_ab*)(bp + f * 32);
                c = __builtin_amdgcn_mfma_f32_16x16x32_bf16(a[f], bf, c, 0, 0, 0);
            }
            int col = ct * 16 + m;
            float bv = bias[col];
            if (do_pool) {
#pragma unroll
                for (int r = 0; r < 4; ++r) {
                    int nr = nrow_base + r;
                    if (nr < n) {
                        float v = fmaxf(c[r] + bv, 0.f);
                        atomicAdd(&gsum[(size_t)batch[nr] * 64 + col], v);
                    }
                }
            } else {
#pragma unroll
                for (int r = 0; r < 4; ++r) {
                    int nr = nrow_base + r;
                    if (nr < n) out[(size_t)nr * 64 + col] = f2bf(fmaxf(c[r] + bv, 0.f));
                }
            }
        }
    }

    if (do_pool) {  // ---- last block runs the classifier ----
        __syncthreads();
        if (t == 0) {
            __threadfence();
            int old = __hip_atomic_fetch_add(done, 1, __ATOMIC_ACQ_REL,
                                             __HIP_MEMORY_SCOPE_AGENT);
            winner = (old == (int)gridDim.x - 1) ? 1 : 0;
        }
        __syncthreads();
        if (winner) {
            for (int g = t; g < G; g += 256) {
                int s = gstart[g], e = gstart[g + 1];
                float invc = 1.0f / fmaxf((float)(e - s), 1.0f);
                float o0 = 0.f, o1 = 0.f, o2 = 0.f, o3 = 0.f;
                for (int hh = 0; hh < 64; ++hh) {
                    float hv = __hip_atomic_load(&gsum[(size_t)g * 64 + hh],
                                                 __ATOMIC_RELAXED,
                                                 __HIP_MEMORY_SCOPE_AGENT);
                    float mmean = hv * invc;
                    o0 += mmean * clas_w[hh * 4 + 0];
                    o1 += mmean * clas_w[hh * 4 + 1];
                    o2 += mmean * clas_w[hh * 4 + 2];
                    o3 += mmean * clas_w[hh * 4 + 3];
                }
                gout[g * 4 + 0] = o0 + clas_b[0];
                gout[g * 4 + 1] = o1 + clas_b[1];
                gout[g * 4 + 2] = o2 + clas_b[2];
                gout[g * 4 + 3] = o3 + clas_b[3];
            }
        }
    }
}

extern "C" void kernel_launch(void* const* d_in, const int* in_sizes, int n_in,
                              void* d_out, int out_size, void* d_ws, size_t ws_size,
                              hipStream_t stream) {
    const float* x        = (const float*)d_in[0];
    const int* edge_index = (const int*)d_in[1];
    const int* edge_type  = (const int*)d_in[2];
    const int* batch      = (const int*)d_in[3];
    const float* basis1 = (const float*)d_in[4];
    const float* comp1  = (const float*)d_in[5];
    const float* root1  = (const float*)d_in[6];
    const float* bias1  = (const float*)d_in[7];
    const float* basis2 = (const float*)d_in[8];
    const float* comp2  = (const float*)d_in[9];
    const float* root2  = (const float*)d_in[10];
    const float* bias2  = (const float*)d_in[11];
    const float* clas_w = (const float*)d_in[12];
    const float* clas_b = (const float*)d_in[13];

    const int N = in_sizes[0] / 64;
    const int E = in_sizes[2];
    const int G = out_size / 4;
    const int* src = edge_index;
    const int* dst = edge_index + E;
    const int nbuck = (N + 255) >> 8;

    char* base = (char*)d_ws;
    size_t off = 0;
    auto carve = [&](size_t bytes) { void* p = base + off; off = (off + bytes + 15) & ~(size_t)15; return p; };
    int*   cur     = (int*)carve(sizeof(int) * 256);
    int*   done    = (int*)carve(sizeof(int) * 4);
    float* gsum    = (float*)carve(sizeof(float) * (size_t)G * HH);
    int*   rpflat  = (int*)carve(sizeof(int) * ((size_t)N * 4 + 4));
    int*   gstart  = (int*)carve(sizeof(int) * ((size_t)G + 1));
    int*   eidx    = (int*)carve(sizeof(int) * (size_t)E);
    int*   tmp     = (int*)carve(sizeof(int) * (size_t)nbuck * CAP);
    short* W1t     = (short*)carve(sizeof(short) * LWN);
    short* W2t     = (short*)carve(sizeof(short) * LWN);
    short* Xb1     = (short*)carve(sizeof(short) * (size_t)N * 64);
    short* H1      = (short*)carve(sizeof(short) * (size_t)N * 64);
    float* gout    = (float*)d_out;

    const int zb  = (G * HH + 255) / 256;
    const int wbl = (2 * LWN + 255) / 256;
    const int nb  = (N + 255) / 256;
    const int cvb = (N * 64 / 4 + 255) / 256;
    const int prep_blocks = zb + wbl + nb + cvb;
    const int ebl = (E + EPB - 1) / EPB;
    const int layer_blocks = (N + 31) / 32;

    prep_kernel<<<prep_blocks, 256, 0, stream>>>(
        basis1, comp1, root1, basis2, comp2, root2, W1t, W2t,
        batch, gstart, N, G, x, Xb1, cur, gsum, done, rpflat, E,
        zb, wbl, nb);
    bin_kernel<<<ebl, 256, 0, stream>>>(src, dst, edge_type, cur, tmp, E);
    csr_kernel<<<nbuck, 256, 0, stream>>>(cur, tmp, rpflat, eidx, N);

    layer_kernel<<<layer_blocks, 256, 0, stream>>>(
        rpflat, eidx, Xb1, W1t, bias1, H1, N, 0,
        batch, gsum, done, gstart, G, clas_w, clas_b, gout);
    layer_kernel<<<layer_blocks, 256, 0, stream>>>(
        rpflat, eidx, H1, W2t, bias2, nullptr, N, 1,
        batch, gsum, done, gstart, G, clas_w, clas_b, gout);
}

// Round 6
// 219.554 us; speedup vs baseline: 2.2777x; 1.4306x over previous
//
#include <hip/hip_runtime.h>

// H2G2: 2-layer RGCN (R=4, per-relation mean) + mean-pool + linear.
// R10: register-resident fused layer (231us total, layer 47us). R11 FAILED:
//   launch_bounds(256,4) VGPR cap -> scratch spill (layer 221us). Never cap.
// R12 (229.6us): channel-split wave pair, merged one-hot loop, 8KB LDS
//   exchange: layer pinned at 47.0us == R10. FETCH 52MB = 8 XCD x 6.4MB full
//   per-XCD L2 replication at ~1 line/cy/XCD -> layer is L2-FILL-BOUND.
// R13 FAILED (282.6us): direct CSR place = random 4B global writes = line RMW.
// R14 FAILED (500us+): cooperative grid.sync ~80-90us each w/ mostly-idle grid.
// R15 (314us): (a) fixed-CAP bucket reservation WORKED (histogram/scan
//   machinery deleted); (b) pool-fused layer2 FAILED: 3.2M device-scope fp32
//   atomicAdd -> memory-side coherence point (XCD L2s non-coherent) = 150us
//   (WRITE 23.3MB ~= 3.2M x 7B). Rule: no per-element device-scope atomics.
// R16: keep (a), revert (b). Merge prep INTO the bin dispatch (bin only needs
//   cur==0 -> 1KB hipMemsetAsync). Pipeline: memset -> work(bin+weights+
//   gstart+xconv) -> csr -> layer1 -> layer2 -> pool = 5 kernels + memset.

#define RR 4
#define HH 64
#define KK 320         // (RR+1)*HH
#define LWN (HH * KK)  // weights per layer = 20480
#define EPB 2048       // edges per bin chunk
#define CAP 6144       // per-bucket fixed capacity (mean 4096, +32 sigma)

using frag_ab = __attribute__((ext_vector_type(8))) short;
using frag_cd = __attribute__((ext_vector_type(4))) float;

__device__ inline short f2bf(float f) {
    unsigned u = __builtin_bit_cast(unsigned, f);
    unsigned r = u + 0x7fffu + ((u >> 16) & 1u);  // RNE
    return (short)(r >> 16);
}
__device__ inline float bf2f(short s) {
    unsigned u = ((unsigned)(unsigned short)s) << 16;
    return __builtin_bit_cast(float, u);
}

// ---- work: bin chunks | weights | gstart+sentinel | x conv (one dispatch) ----
__global__ __launch_bounds__(256) void work_kernel(
    const int* __restrict__ src, const int* __restrict__ dst,
    const int* __restrict__ et, int E,
    int* __restrict__ cur, int* __restrict__ tmp,
    const float* __restrict__ basis1, const float* __restrict__ comp1, const float* __restrict__ root1,
    const float* __restrict__ basis2, const float* __restrict__ comp2, const float* __restrict__ root2,
    short* __restrict__ W1t, short* __restrict__ W2t,
    const int* __restrict__ batch, int* __restrict__ gstart, int N, int G,
    int* __restrict__ rpflat,
    const float* __restrict__ x, short* __restrict__ Xb,
    int ebl, int wbl, int nb) {
    __shared__ int ss[256];
    __shared__ int lscan[257];
    __shared__ int lbase[256];
    __shared__ int lc2[256];
    __shared__ int sbuf[EPB];
    const int bid = blockIdx.x;
    const int t = threadIdx.x;

    if (bid < ebl) {  // ---- bin: LDS-staged bucket scatter into CAP regions ----
        const int e0 = bid * EPB;
        const int e1 = min(e0 + EPB, E);
        ss[t] = 0;
        __syncthreads();
        for (int e = e0 + t; e < e1; e += 256) atomicAdd(&ss[dst[e] >> 8], 1);
        __syncthreads();
        int v = ss[t];
        __syncthreads();
#pragma unroll
        for (int off = 1; off < 256; off <<= 1) {
            int u = (t >= off) ? ss[t - off] : 0;
            __syncthreads();
            ss[t] += u;
            __syncthreads();
        }
        lscan[t] = ss[t] - v;
        if (t == 255) lscan[256] = ss[255];
        lbase[t] = v ? t * CAP + atomicAdd(&cur[t], v) : 0;  // reserve
        lc2[t] = 0;
        __syncthreads();
        for (int e = e0 + t; e < e1; e += 256) {
            int d = dst[e];
            int b = d >> 8;
            int p = (src[e] << 10) | (et[e] << 8) | (d & 255);
            int pos = lscan[b] + atomicAdd(&lc2[b], 1);
            sbuf[pos] = p;
        }
        __syncthreads();
        int tot = lscan[256];
        for (int i = t; i < tot; i += 256) {
            int lo = 0, hi = 255;
            while (lo < hi) { int mid = (lo + hi + 1) >> 1; if (lscan[mid] <= i) lo = mid; else hi = mid - 1; }
            int idx = lbase[lo] + (i - lscan[lo]);
            if (idx - lo * CAP < CAP) tmp[idx] = sbuf[i];  // overflow shield
        }
    } else if (bid < ebl + wbl) {  // ---- weights: Wt[c*320+k] = Wstack[k][c] ----
        int w = (bid - ebl) * 256 + t;
        int layer = w / LWN;
        int rem = w - layer * LWN;
        int c = rem / KK;
        int k = rem - c * KK;
        const float* basis = layer ? basis2 : basis1;
        const float* comp  = layer ? comp2  : comp1;
        const float* root  = layer ? root2  : root1;
        short* Wt          = layer ? W2t    : W1t;
        float v;
        if (k < HH) {
            v = root[k * HH + c];
        } else {
            int r = (k >> 6) - 1, kk = k & 63;
            v = 0.f;
#pragma unroll
            for (int b = 0; b < RR; ++b) v += comp[r * RR + b] * basis[(b * HH + kk) * HH + c];
        }
        Wt[c * KK + k] = f2bf(v);
    } else if (bid < ebl + wbl + nb) {  // ---- gstart + rpflat sentinel ----
        int i = (bid - ebl - wbl) * 256 + t;
        if (i == 0) rpflat[4 * N] = E;
        if (i < N) {
            int b1 = batch[i];
            int b0 = (i == 0) ? -1 : batch[i - 1];
            for (int g = b0 + 1; g <= b1; ++g) gstart[g] = i;
            if (i == N - 1)
                for (int g = b1 + 1; g <= G; ++g) gstart[g] = N;
        }
    } else {  // ---- convert x fp32 -> bf16 ----
        int i4 = (bid - ebl - wbl - nb) * 256 + t;
        int base = i4 * 4;
        if (base < N * 64) {
            float4 f = *(const float4*)&x[base];
            short4 s;
            s.x = f2bf(f.x); s.y = f2bf(f.y); s.z = f2bf(f.z); s.w = f2bf(f.w);
            *(short4*)&Xb[base] = s;
        }
    }
}

// ---- csr: per-bucket (dl,rel) counting sort -> rpflat int4 + compact eidx ----
__global__ __launch_bounds__(256) void csr_kernel(const int* __restrict__ cur,
                                                  const int* __restrict__ tmp,
                                                  int* __restrict__ rpflat,
                                                  int* __restrict__ eidx, int N) {
    __shared__ int cnt4l[1024];
    __shared__ int ss[256];
    __shared__ int s0s, lens;
    const int b = blockIdx.x;
    const int t = threadIdx.x;
    // compact global start: scan bucket lengths
    int lv = min(cur[t], CAP);
    ss[t] = lv;
    __syncthreads();
#pragma unroll
    for (int off = 1; off < 256; off <<= 1) {
        int u = (t >= off) ? ss[t - off] : 0;
        __syncthreads();
        ss[t] += u;
        __syncthreads();
    }
    if (t == b) { s0s = ss[t] - lv; lens = lv; }
    __syncthreads();
    const int s0 = s0s, len = lens;
    const int tb = b * CAP;

    for (int i = t; i < 1024; i += 256) cnt4l[i] = 0;
    __syncthreads();
    for (int i = t; i < len; i += 256) {
        int e = tmp[tb + i];
        atomicAdd(&cnt4l[((e & 255) << 2) | ((e >> 8) & 3)], 1);
    }
    __syncthreads();
    int c0 = cnt4l[t * 4], c1 = cnt4l[t * 4 + 1], c2 = cnt4l[t * 4 + 2], c3 = cnt4l[t * 4 + 3];
    int deg = c0 + c1 + c2 + c3;
    ss[t] = deg;
    __syncthreads();
#pragma unroll
    for (int off = 1; off < 256; off <<= 1) {
        int u = (t >= off) ? ss[t - off] : 0;
        __syncthreads();
        ss[t] += u;
        __syncthreads();
    }
    int a0 = s0 + ss[t] - deg;
    int d = (b << 8) + t;
    if (d < N)
        *(int4*)&rpflat[d * 4] = make_int4(a0, a0 + c0, a0 + c0 + c1, a0 + c0 + c1 + c2);
    cnt4l[t * 4]     = a0;
    cnt4l[t * 4 + 1] = a0 + c0;
    cnt4l[t * 4 + 2] = a0 + c0 + c1;
    cnt4l[t * 4 + 3] = a0 + c0 + c1 + c2;
    __syncthreads();
    for (int i = t; i < len; i += 256) {
        int e = tmp[tb + i];
        int key = ((e & 255) << 2) | ((e >> 8) & 3);
        int pos = atomicAdd(&cnt4l[key], 1);
        eidx[pos] = ((e >> 10) << 2) | ((e >> 8) & 3);
    }
}

// ---- fused layer (R12 body): 32 nodes/block; wave pair splits CHANNELS.
// ws=0 gathers low 8ch of its quad, ws=1 high 8ch; both walk the full edge
// list (merged one-hot accumulate, 4 edges in flight). ws=1 packs bf16 frags
// into 8KB LDS; ws=0 runs K=320 MFMA. inv derived from rpflat diffs. ----
__global__ __launch_bounds__(256) void layer_kernel(
    const int* __restrict__ rpflat,
    const int* __restrict__ eidx,
    const short* __restrict__ Xb,
    const short* __restrict__ Wt,
    const float* __restrict__ bias,
    short* __restrict__ out, int n) {
    __shared__ short xpack[2][64][32];  // 8KB
    const int t = threadIdx.x;
    const int wv = t >> 6;
    const int pair = wv >> 1;   // which 16-node group
    const int ws = wv & 1;      // channel half: 0 = quad*8, 1 = 32+quad*8
    const int l = t & 63;
    const int m = l & 15;
    const int quad = l >> 4;
    const int node = blockIdx.x * 32 + pair * 16 + m;
    const bool valid = node < n;

    float acc[4][8];
#pragma unroll
    for (int r = 0; r < 4; ++r)
#pragma unroll
        for (int j = 0; j < 8; ++j) acc[r][j] = 0.f;

    int k0 = 0, k1 = 0;
    float4 iv = make_float4(0.f, 0.f, 0.f, 0.f);
    if (valid) {
        int4 r4 = *(const int4*)&rpflat[node * 4];
        int kend = rpflat[node * 4 + 4];
        k0 = r4.x;
        k1 = kend;
        iv.x = 1.0f / fmaxf((float)(r4.y - r4.x), 1.0f);
        iv.y = 1.0f / fmaxf((float)(r4.z - r4.y), 1.0f);
        iv.z = 1.0f / fmaxf((float)(r4.w - r4.z), 1.0f);
        iv.w = 1.0f / fmaxf((float)(kend - r4.w), 1.0f);
    }
    const short* xbq = Xb + ws * 32 + quad * 8;

#define ACC(P, F)                                                             \
    {                                                                         \
        int r_ = (P) & 3;                                                     \
        float s0_ = (r_ == 0) ? 1.f : 0.f;                                    \
        float s1_ = (r_ == 1) ? 1.f : 0.f;                                    \
        float s2_ = (r_ == 2) ? 1.f : 0.f;                                    \
        float s3_ = (r_ == 3) ? 1.f : 0.f;                                    \
        _Pragma("unroll") for (int j = 0; j < 8; ++j) {                       \
            float v_ = bf2f((F)[j]);                                          \
            acc[0][j] += v_ * s0_;                                            \
            acc[1][j] += v_ * s1_;                                            \
            acc[2][j] += v_ * s2_;                                            \
            acc[3][j] += v_ * s3_;                                            \
        }                                                                     \
    }

    int k = k0;
    for (; k + 3 < k1; k += 4) {  // 4 edges in flight
        int p0 = eidx[k];
        int p1 = eidx[k + 1];
        int p2 = eidx[k + 2];
        int p3 = eidx[k + 3];
        const short* a0p = xbq + (size_t)(p0 >> 2) * 64;
        const short* a1p = xbq + (size_t)(p1 >> 2) * 64;
        const short* a2p = xbq + (size_t)(p2 >> 2) * 64;
        const short* a3p = xbq + (size_t)(p3 >> 2) * 64;
        frag_ab f0 = *(const frag_ab*)a0p;
        frag_ab f1 = *(const frag_ab*)a1p;
        frag_ab f2 = *(const frag_ab*)a2p;
        frag_ab f3 = *(const frag_ab*)a3p;
        ACC(p0, f0)
        ACC(p1, f1)
        ACC(p2, f2)
        ACC(p3, f3)
    }
    for (; k < k1; ++k) {
        int p0 = eidx[k];
        const short* a0p = xbq + (size_t)(p0 >> 2) * 64;
        frag_ab f0 = *(const frag_ab*)a0p;
        ACC(p0, f0)
    }
#undef ACC

    frag_ab y[4];
    {
        float s0 = iv.x, s1 = iv.y, s2 = iv.z, s3 = iv.w;
#pragma unroll
        for (int j = 0; j < 8; ++j) {
            y[0][j] = f2bf(acc[0][j] * s0);
            y[1][j] = f2bf(acc[1][j] * s1);
            y[2][j] = f2bf(acc[2][j] * s2);
            y[3][j] = f2bf(acc[3][j] * s3);
        }
    }

    if (ws == 1) {
#pragma unroll
        for (int r = 0; r < 4; ++r)
            *(frag_ab*)&xpack[pair][l][r * 8] = y[r];
    }
    __syncthreads();
    if (ws == 1) return;

    frag_ab a[10];
    a[0] = frag_ab{};
    a[1] = frag_ab{};
    if (valid) {
        const short* xr = Xb + (size_t)node * 64 + quad * 8;
        a[0] = *(const frag_ab*)xr;
        a[1] = *(const frag_ab*)(xr + 32);
    }
#pragma unroll
    for (int r = 0; r < 4; ++r) {
        a[2 + 2 * r] = y[r];
        a[3 + 2 * r] = *(const frag_ab*)&xpack[pair][l][r * 8];
    }

    const int nrow_base = blockIdx.x * 32 + pair * 16 + quad * 4;
#pragma unroll
    for (int ct = 0; ct < 4; ++ct) {
        const short* bp = Wt + (size_t)(ct * 16 + m) * KK + quad * 8;
        frag_cd c = {0.f, 0.f, 0.f, 0.f};
#pragma unroll
        for (int f = 0; f < 10; ++f) {
            frag_ab bf = *(const frag_ab*)(bp + f * 32);
            c = __builtin_amdgcn_mfma_f32_16x16x32_bf16(a[f], bf, c, 0, 0, 0);
        }
        int col = ct * 16 + m;
        float bv = bias[col];
#pragma unroll
        for (int r = 0; r < 4; ++r) {
            int nr = nrow_base + r;
            if (nr < n) out[(size_t)nr * 64 + col] = f2bf(fmaxf(c[r] + bv, 0.f));
        }
    }
}

// ---- pool (segmented) + classifier ----
__global__ __launch_bounds__(256) void pool_cls_kernel(const short* __restrict__ h2,
                                                       const int* __restrict__ gstart,
                                                       const float* __restrict__ w,
                                                       const float* __restrict__ b,
                                                       float* __restrict__ out) {
    __shared__ float red[4][64];
    const int g = blockIdx.x;
    const int t = threadIdx.x;
    const int h = t & 63;
    const int wv = t >> 6;
    const int s = gstart[g], e = gstart[g + 1];

    float acc = 0.f;
    for (int i = s + wv; i < e; i += 4) acc += bf2f(h2[(size_t)i * 64 + h]);
    red[wv][h] = acc;
    __syncthreads();
    if (wv == 0) {
        float sum = red[0][h] + red[1][h] + red[2][h] + red[3][h];
        red[0][h] = sum / fmaxf((float)(e - s), 1.0f);
    }
    __syncthreads();
    if (t < 4) {
        float sres = 0.f;
#pragma unroll 8
        for (int hh = 0; hh < 64; ++hh) sres += red[0][hh] * w[hh * 4 + t];
        out[g * 4 + t] = sres + b[t];
    }
}

extern "C" void kernel_launch(void* const* d_in, const int* in_sizes, int n_in,
                              void* d_out, int out_size, void* d_ws, size_t ws_size,
                              hipStream_t stream) {
    const float* x        = (const float*)d_in[0];
    const int* edge_index = (const int*)d_in[1];
    const int* edge_type  = (const int*)d_in[2];
    const int* batch      = (const int*)d_in[3];
    const float* basis1 = (const float*)d_in[4];
    const float* comp1  = (const float*)d_in[5];
    const float* root1  = (const float*)d_in[6];
    const float* bias1  = (const float*)d_in[7];
    const float* basis2 = (const float*)d_in[8];
    const float* comp2  = (const float*)d_in[9];
    const float* root2  = (const float*)d_in[10];
    const float* bias2  = (const float*)d_in[11];
    const float* clas_w = (const float*)d_in[12];
    const float* clas_b = (const float*)d_in[13];

    const int N = in_sizes[0] / 64;
    const int E = in_sizes[2];
    const int G = out_size / 4;
    const int* src = edge_index;
    const int* dst = edge_index + E;
    const int nbuck = (N + 255) >> 8;

    char* base = (char*)d_ws;
    size_t off = 0;
    auto carve = [&](size_t bytes) { void* p = base + off; off = (off + bytes + 15) & ~(size_t)15; return p; };
    int*   cur     = (int*)carve(sizeof(int) * 256);
    int*   rpflat  = (int*)carve(sizeof(int) * ((size_t)N * 4 + 4));
    int*   gstart  = (int*)carve(sizeof(int) * ((size_t)G + 1));
    int*   eidx    = (int*)carve(sizeof(int) * (size_t)E);
    int*   tmp     = (int*)carve(sizeof(int) * (size_t)nbuck * CAP);
    short* W1t     = (short*)carve(sizeof(short) * LWN);
    short* W2t     = (short*)carve(sizeof(short) * LWN);
    short* Xb1     = (short*)carve(sizeof(short) * (size_t)N * 64);
    short* H1      = (short*)carve(sizeof(short) * (size_t)N * 64);
    short* H2      = (short*)carve(sizeof(short) * (size_t)N * 64);
    float* gout    = (float*)d_out;

    const int ebl = (E + EPB - 1) / EPB;
    const int wbl = (2 * LWN + 255) / 256;
    const int nb  = (N + 255) / 256;
    const int cvb = (N * 64 / 4 + 255) / 256;
    const int work_blocks = ebl + wbl + nb + cvb;
    const int layer_blocks = (N + 31) / 32;

    hipMemsetAsync(cur, 0, sizeof(int) * 256, stream);

    work_kernel<<<work_blocks, 256, 0, stream>>>(
        src, dst, edge_type, E, cur, tmp,
        basis1, comp1, root1, basis2, comp2, root2, W1t, W2t,
        batch, gstart, N, G, rpflat, x, Xb1, ebl, wbl, nb);
    csr_kernel<<<nbuck, 256, 0, stream>>>(cur, tmp, rpflat, eidx, N);

    layer_kernel<<<layer_blocks, 256, 0, stream>>>(rpflat, eidx, Xb1, W1t, bias1, H1, N);
    layer_kernel<<<layer_blocks, 256, 0, stream>>>(rpflat, eidx, H1, W2t, bias2, H2, N);

    pool_cls_kernel<<<G, 256, 0, stream>>>(H2, gstart, clas_w, clas_b, gout);
}